// Round 1
// baseline (466.838 us; speedup 1.0000x reference)
//
#include <hip/hip_runtime.h>

#define IMG 512
#define CIN 32
#define COUT 32
#define NORI 8
#define HW (IMG*IMG)

// tw layout: tw[((r*9 + k)*CIN + c)*COUT + o]
__global__ void build_tw_kernel(const float* __restrict__ weight, float* __restrict__ tw) {
    int idx = blockIdx.x * blockDim.x + threadIdx.x; // 0..1023
    if (idx >= COUT * CIN) return;
    int o = idx / CIN, c = idx % CIN;
    float b[9];
#pragma unroll
    for (int t = 0; t < 9; ++t) b[t] = weight[(o * CIN + c) * 9 + t];

    // rotate_kernel(base, 45deg): out(i,j) = bilinear sample of b at rotated coords
    float w45[9];
    const float cs = 0.70710678f; // cos(45)=sin(45) as float32
#pragma unroll
    for (int i = 0; i < 3; ++i) {
#pragma unroll
        for (int j = 0; j < 3; ++j) {
            float ys = cs * (float)(i - 1) + cs * (float)(j - 1) + 1.0f;
            float xs = -cs * (float)(i - 1) + cs * (float)(j - 1) + 1.0f;
            float y0f = floorf(ys), x0f = floorf(xs);
            float wy = ys - y0f, wx = xs - x0f;
            int iy0 = (int)y0f, ix0 = (int)x0f;
            float acc = 0.0f;
#pragma unroll
            for (int dy = 0; dy < 2; ++dy) {
#pragma unroll
                for (int dx = 0; dx < 2; ++dx) {
                    int iy = iy0 + dy, ix = ix0 + dx;
                    float wgt = (dy ? wy : 1.0f - wy) * (dx ? wx : 1.0f - wx);
                    bool valid = (iy >= 0) && (iy < 3) && (ix >= 0) && (ix < 3);
                    int iyc = min(max(iy, 0), 2), ixc = min(max(ix, 0), 2);
                    acc += b[iyc * 3 + ixc] * (valid ? wgt : 0.0f);
                }
            }
            w45[i * 3 + j] = acc;
        }
    }

    // 8 orientations: r=0..3 -> rot90^r(base); r=4..7 -> rot90^(r-4)(w45)
    // np.rot90 k=1: out[i,j] = src[j, 2-i]
#pragma unroll
    for (int r = 0; r < NORI; ++r) {
        const float* src = (r < 4) ? b : w45;
        int rr = r & 3;
#pragma unroll
        for (int i = 0; i < 3; ++i) {
#pragma unroll
            for (int j = 0; j < 3; ++j) {
                int si, sj;
                if (rr == 0) { si = i;     sj = j;     }
                else if (rr == 1) { si = j;     sj = 2 - i; }
                else if (rr == 2) { si = 2 - i; sj = 2 - j; }
                else { si = 2 - j; sj = i;     }
                tw[(((r * 9) + (i * 3 + j)) * CIN + c) * COUT + o] = src[si * 3 + sj];
            }
        }
    }
}

__global__ __launch_bounds__(256) void fused_deform_kernel(
    const float* __restrict__ x,
    const float* __restrict__ offw, const float* __restrict__ offb,
    const float* __restrict__ mskw, const float* __restrict__ mskb,
    const float* __restrict__ gm,
    const float* __restrict__ tw,
    float* __restrict__ out)
{
    const int tiles_x = IMG / 16;
    int bx = blockIdx.x % tiles_x, by = blockIdx.x / tiles_x;
    int tx = threadIdx.x & 15, ty = threadIdx.x >> 4;
    int X = bx * 16 + tx, Y = by * 16 + ty;
    int p = Y * IMG + X;

    // ---- phase 1: offset (18ch) + mask (9ch) 3x3 conv at this pixel ----
    float acc[27];
#pragma unroll
    for (int i = 0; i < 18; ++i) acc[i] = offb[i];
#pragma unroll
    for (int i = 0; i < 9; ++i) acc[18 + i] = mskb[i];

    for (int c = 0; c < CIN; ++c) {
        const float* xc = x + c * HW;
        float v[9];
#pragma unroll
        for (int ky = 0; ky < 3; ++ky) {
            int yy = Y + ky - 1;
            bool vy = ((unsigned)yy < (unsigned)IMG);
#pragma unroll
            for (int kx = 0; kx < 3; ++kx) {
                int xx = X + kx - 1;
                bool ok = vy && ((unsigned)xx < (unsigned)IMG);
                v[ky * 3 + kx] = ok ? xc[yy * IMG + xx] : 0.0f;
            }
        }
        // weight addresses are wave-uniform (loop counters only) -> expect s_load
        const float* wo = offw + c * 9;
#pragma unroll
        for (int oc = 0; oc < 18; ++oc) {
#pragma unroll
            for (int t = 0; t < 9; ++t)
                acc[oc] = fmaf(v[t], wo[oc * CIN * 9 + t], acc[oc]);
        }
        const float* wm = mskw + c * 9;
#pragma unroll
        for (int oc = 0; oc < 9; ++oc) {
#pragma unroll
            for (int t = 0; t < 9; ++t)
                acc[18 + oc] = fmaf(v[t], wm[oc * CIN * 9 + t], acc[18 + oc]);
        }
    }
    // offset[:, 8:10] = 0  (center tap offsets), modm ch4 = 0 pre-sigmoid
    acc[8] = 0.0f; acc[9] = 0.0f;
    acc[18 + 4] = 0.0f;
    float modm[9];
#pragma unroll
    for (int i = 0; i < 9; ++i) modm[i] = 1.0f / (1.0f + __expf(-acc[18 + i]));

    // ---- sector from one-hot group_mask ----
    int r = 0;
#pragma unroll
    for (int n = 1; n < NORI; ++n) r = (gm[n * HW + p] > 0.5f) ? n : r;

    // ---- phase 2: deformable sampling + GEMV against tw[r] + relu ----
    float oacc[32];
#pragma unroll
    for (int o = 0; o < 32; ++o) oacc[o] = 0.0f;

#pragma unroll
    for (int k = 0; k < 9; ++k) {
        const int ky = k / 3, kx = k % 3;
        float pyf = (float)(Y - 1 + ky) + acc[2 * k];
        float pxf = (float)(X - 1 + kx) + acc[2 * k + 1];
        float y0f = floorf(pyf), x0f = floorf(pxf);
        float wy = pyf - y0f, wx = pxf - x0f;
        int iy0 = (int)y0f, ix0 = (int)x0f;
        int iy1 = iy0 + 1, ix1 = ix0 + 1;
        float m = modm[k];
        float vy0 = ((unsigned)iy0 < (unsigned)IMG) ? 1.0f : 0.0f;
        float vy1 = ((unsigned)iy1 < (unsigned)IMG) ? 1.0f : 0.0f;
        float vx0 = ((unsigned)ix0 < (unsigned)IMG) ? 1.0f : 0.0f;
        float vx1 = ((unsigned)ix1 < (unsigned)IMG) ? 1.0f : 0.0f;
        int cy0 = min(max(iy0, 0), IMG - 1), cy1 = min(max(iy1, 0), IMG - 1);
        int cx0 = min(max(ix0, 0), IMG - 1), cx1 = min(max(ix1, 0), IMG - 1);
        float w00 = m * (1.0f - wy) * (1.0f - wx) * vy0 * vx0;
        float w01 = m * (1.0f - wy) * wx * vy0 * vx1;
        float w10 = m * wy * (1.0f - wx) * vy1 * vx0;
        float w11 = m * wy * wx * vy1 * vx1;
        int o00 = cy0 * IMG + cx0, o01 = cy0 * IMG + cx1;
        int o10 = cy1 * IMG + cx0, o11 = cy1 * IMG + cx1;

        const float* twk = tw + (r * 9 + k) * CIN * COUT;
        const float* xc = x;
        for (int c = 0; c < CIN; ++c) {
            float s = w00 * xc[o00] + w01 * xc[o01] + w10 * xc[o10] + w11 * xc[o11];
            const float4* t4p = (const float4*)(twk + c * COUT);
#pragma unroll
            for (int oq = 0; oq < 8; ++oq) {
                float4 t4 = t4p[oq];
                oacc[oq * 4 + 0] = fmaf(s, t4.x, oacc[oq * 4 + 0]);
                oacc[oq * 4 + 1] = fmaf(s, t4.y, oacc[oq * 4 + 1]);
                oacc[oq * 4 + 2] = fmaf(s, t4.z, oacc[oq * 4 + 2]);
                oacc[oq * 4 + 3] = fmaf(s, t4.w, oacc[oq * 4 + 3]);
            }
            xc += HW;
        }
    }

#pragma unroll
    for (int o = 0; o < 32; ++o) out[o * HW + p] = fmaxf(oacc[o], 0.0f);
}

extern "C" void kernel_launch(void* const* d_in, const int* in_sizes, int n_in,
                              void* d_out, int out_size, void* d_ws, size_t ws_size,
                              hipStream_t stream) {
    const float* x      = (const float*)d_in[0];
    const float* weight = (const float*)d_in[1];
    const float* offw   = (const float*)d_in[2];
    const float* offb   = (const float*)d_in[3];
    const float* mskw   = (const float*)d_in[4];
    const float* mskb   = (const float*)d_in[5];
    const float* gm     = (const float*)d_in[6];
    float* out = (float*)d_out;
    float* tw  = (float*)d_ws; // 8*9*32*32*4 = 294912 bytes

    build_tw_kernel<<<4, 256, 0, stream>>>(weight, tw);

    const int tiles = (IMG / 16) * (IMG / 16); // 1024 blocks
    fused_deform_kernel<<<tiles, 256, 0, stream>>>(x, offw, offb, mskw, mskb, gm, tw, out);
}